// Round 1
// baseline (73.374 us; speedup 1.0000x reference)
//
#include <hip/hip_runtime.h>

#define BS  16
#define NN  256
#define HID 128

// ---------------------------------------------------------------------------
// K1: per 8-row tile compute h = x@W_fc + b_fc, ai = h@W_a1[:H] + b_a1,
//     aj = h@W_a1[H:]. 128 threads (thread = output column k), 512 blocks.
// ---------------------------------------------------------------------------
__global__ __launch_bounds__(128) void gat_k1(
    const float* __restrict__ x, const float* __restrict__ W_fc,
    const float* __restrict__ b_fc, const float* __restrict__ W_a1,
    const float* __restrict__ b_a1,
    float* __restrict__ h, float* __restrict__ ai, float* __restrict__ aj)
{
    __shared__ __align__(16) float xs[8][HID];
    __shared__ __align__(16) float hs[8][HID];
    const int k  = threadIdx.x;
    const int r0 = blockIdx.x * 8;

    #pragma unroll
    for (int r = 0; r < 8; ++r) xs[r][k] = x[(r0 + r) * HID + k];
    __syncthreads();

    // phase 1: h
    float acc[8];
    const float bf = b_fc[k];
    #pragma unroll
    for (int r = 0; r < 8; ++r) acc[r] = bf;
    for (int d0 = 0; d0 < HID; d0 += 4) {
        const float w0 = W_fc[(d0 + 0) * HID + k];
        const float w1 = W_fc[(d0 + 1) * HID + k];
        const float w2 = W_fc[(d0 + 2) * HID + k];
        const float w3 = W_fc[(d0 + 3) * HID + k];
        #pragma unroll
        for (int r = 0; r < 8; ++r) {
            const float4 xv = *(const float4*)&xs[r][d0];
            acc[r] += xv.x * w0 + xv.y * w1 + xv.z * w2 + xv.w * w3;
        }
    }
    #pragma unroll
    for (int r = 0; r < 8; ++r) { hs[r][k] = acc[r]; h[(r0 + r) * HID + k] = acc[r]; }
    __syncthreads();

    // phase 2: ai (bakes in b_a1), aj
    float ai_acc[8], aj_acc[8];
    const float b1 = b_a1[k];
    #pragma unroll
    for (int r = 0; r < 8; ++r) { ai_acc[r] = b1; aj_acc[r] = 0.f; }
    for (int d0 = 0; d0 < HID; d0 += 4) {
        float wi[4], wj[4];
        #pragma unroll
        for (int t = 0; t < 4; ++t) {
            wi[t] = W_a1[(d0 + t) * HID + k];
            wj[t] = W_a1[(HID + d0 + t) * HID + k];
        }
        #pragma unroll
        for (int r = 0; r < 8; ++r) {
            const float4 hv = *(const float4*)&hs[r][d0];
            ai_acc[r] += hv.x * wi[0] + hv.y * wi[1] + hv.z * wi[2] + hv.w * wi[3];
            aj_acc[r] += hv.x * wj[0] + hv.y * wj[1] + hv.z * wj[2] + hv.w * wj[3];
        }
    }
    #pragma unroll
    for (int r = 0; r < 8; ++r) {
        ai[(r0 + r) * HID + k] = ai_acc[r];
        aj[(r0 + r) * HID + k] = aj_acc[r];
    }
}

// ---------------------------------------------------------------------------
// K2: per (batch, 8-row i-tile): e-compute + masked softmax + h' = attn@h +
//     out = h'@W_out + b_out. 256 threads, 512 blocks.
// ---------------------------------------------------------------------------
__global__ __launch_bounds__(256) void gat_k2(
    const float* __restrict__ ai, const float* __restrict__ aj,
    const float* __restrict__ h,  const int* __restrict__ adj,
    const float* __restrict__ w_a2, const float* __restrict__ b_a2,
    const float* __restrict__ W_out, const float* __restrict__ b_out,
    float* __restrict__ out)
{
    __shared__ __align__(16) float ais[8][HID];
    __shared__ __align__(16) float w2s[HID];
    __shared__ __align__(16) float p_lds[8][NN];
    __shared__ __align__(16) float hps[8][HID];
    __shared__ float red[8][4];

    const int tid = threadIdx.x;            // = j for phase A
    const int b   = blockIdx.x >> 5;
    const int i0  = (blockIdx.x & 31) * 8;

    for (int t = tid; t < 8 * HID; t += 256)
        ais[t >> 7][t & 127] = ai[(b * NN + i0 + (t >> 7)) * HID + (t & 127)];
    if (tid < HID) w2s[tid] = w_a2[tid];
    __syncthreads();

    // ---- phase A: e[b, i0..i0+7, j=tid] ----
    float acc[8] = {0, 0, 0, 0, 0, 0, 0, 0};
    const float* ajrow = aj + (b * NN + tid) * HID;
    for (int k0 = 0; k0 < HID; k0 += 4) {
        const float4 av = *(const float4*)(ajrow + k0);
        const float4 wv = *(const float4*)&w2s[k0];
        #pragma unroll
        for (int i = 0; i < 8; ++i) {
            const float4 iv = *(const float4*)&ais[i][k0];
            acc[i] += fmaxf(iv.x + av.x, 0.f) * wv.x
                    + fmaxf(iv.y + av.y, 0.f) * wv.y
                    + fmaxf(iv.z + av.z, 0.f) * wv.z
                    + fmaxf(iv.w + av.w, 0.f) * wv.w;
        }
    }

    const float ba2 = b_a2[0];
    float ev[8];
    #pragma unroll
    for (int i = 0; i < 8; ++i) {
        const int a = adj[(b * NN + i0 + i) * NN + tid];
        ev[i] = a ? (acc[i] + ba2) : -1e9f;
    }

    // ---- masked softmax across j (256 threads = 4 waves) ----
    const int lane = tid & 63, wid = tid >> 6;
    #pragma unroll
    for (int i = 0; i < 8; ++i) {
        float v = ev[i];
        #pragma unroll
        for (int off = 32; off > 0; off >>= 1) v = fmaxf(v, __shfl_xor(v, off));
        if (lane == 0) red[i][wid] = v;
    }
    __syncthreads();
    float p[8];
    #pragma unroll
    for (int i = 0; i < 8; ++i) {
        const float m = fmaxf(fmaxf(red[i][0], red[i][1]), fmaxf(red[i][2], red[i][3]));
        p[i] = __expf(ev[i] - m);
    }
    __syncthreads();   // red about to be reused
    #pragma unroll
    for (int i = 0; i < 8; ++i) {
        float v = p[i];
        #pragma unroll
        for (int off = 32; off > 0; off >>= 1) v += __shfl_xor(v, off);
        if (lane == 0) red[i][wid] = v;
    }
    __syncthreads();
    #pragma unroll
    for (int i = 0; i < 8; ++i) {
        const float s = (red[i][0] + red[i][1]) + (red[i][2] + red[i][3]);
        p_lds[i][tid] = p[i] / s;
    }
    __syncthreads();

    // ---- phase B: h'[i,k] = sum_j p[i][j] * h[b,j,k] ----
    const int k = tid & 127, g = tid >> 7;   // g in {0,1}: rows g*4..g*4+3
    float hp[4] = {0, 0, 0, 0};
    const float* hb = h + b * NN * HID;
    #pragma unroll 4
    for (int j = 0; j < NN; ++j) {
        const float hv = hb[j * HID + k];
        #pragma unroll
        for (int ii = 0; ii < 4; ++ii) hp[ii] += p_lds[g * 4 + ii][j] * hv;
    }
    #pragma unroll
    for (int ii = 0; ii < 4; ++ii) hps[g * 4 + ii][k] = hp[ii];
    __syncthreads();

    // ---- phase C: out = h'@W_out + b_out ----
    float o[4];
    const float bo = b_out[k];
    #pragma unroll
    for (int ii = 0; ii < 4; ++ii) o[ii] = bo;
    for (int d0 = 0; d0 < HID; d0 += 4) {
        const float w0 = W_out[(d0 + 0) * HID + k];
        const float w1 = W_out[(d0 + 1) * HID + k];
        const float w2 = W_out[(d0 + 2) * HID + k];
        const float w3 = W_out[(d0 + 3) * HID + k];
        #pragma unroll
        for (int ii = 0; ii < 4; ++ii) {
            const float4 hv = *(const float4*)&hps[g * 4 + ii][d0];
            o[ii] += hv.x * w0 + hv.y * w1 + hv.z * w2 + hv.w * w3;
        }
    }
    #pragma unroll
    for (int ii = 0; ii < 4; ++ii)
        out[(b * NN + i0 + g * 4 + ii) * HID + k] = o[ii];
}

extern "C" void kernel_launch(void* const* d_in, const int* in_sizes, int n_in,
                              void* d_out, int out_size, void* d_ws, size_t ws_size,
                              hipStream_t stream) {
    const float* x     = (const float*)d_in[0];
    const int*   adj   = (const int*)  d_in[1];
    const float* W_fc  = (const float*)d_in[2];
    const float* b_fc  = (const float*)d_in[3];
    const float* W_a1  = (const float*)d_in[4];
    const float* b_a1  = (const float*)d_in[5];
    const float* w_a2  = (const float*)d_in[6];
    const float* b_a2  = (const float*)d_in[7];
    const float* W_out = (const float*)d_in[8];
    const float* b_out = (const float*)d_in[9];
    float* out = (float*)d_out;

    float* ws = (float*)d_ws;
    float* h  = ws;                       // 16*256*128 floats
    float* ai = ws + BS * NN * HID;       // +524288
    float* aj = ws + 2 * BS * NN * HID;   // +1048576  (total 6 MB)

    gat_k1<<<BS * NN / 8, 128, 0, stream>>>(x, W_fc, b_fc, W_a1, b_a1, h, ai, aj);
    gat_k2<<<BS * (NN / 8), 256, 0, stream>>>(ai, aj, h, adj, w_a2, b_a2,
                                              W_out, b_out, out);
}

// Round 2
// 58.764 us; speedup vs baseline: 1.2486x; 1.2486x over previous
//
#include <hip/hip_runtime.h>

#define BS  16
#define NN  256
#define HID 128

// ---------------------------------------------------------------------------
// K1: 8 flat rows per block, 512 threads (4 quarters of 128 = one k-column
// each). Phase 1: quarter q computes h for rows 2q,2q+1. Phase 2: quarters
// 0,1 compute ai (rows 0-3 / 4-7), quarters 2,3 compute aj and store it
// TRANSPOSED as ajT[b][k][j] so K2's phase A is coalesced.
// ---------------------------------------------------------------------------
__global__ __launch_bounds__(512) void gat_k1(
    const float* __restrict__ x, const float* __restrict__ W_fc,
    const float* __restrict__ b_fc, const float* __restrict__ W_a1,
    const float* __restrict__ b_a1,
    float* __restrict__ h, float* __restrict__ ai, float* __restrict__ ajT)
{
    __shared__ __align__(16) float xs[8][HID];
    __shared__ __align__(16) float hs[8][HID];
    const int tid = threadIdx.x;
    const int k   = tid & 127;
    const int q   = tid >> 7;          // 0..3
    const int r0  = blockIdx.x * 8;    // flat row (= b*NN + n), tile within one batch
    const int b   = r0 >> 8;
    const int n0  = r0 & 255;

    for (int t = tid; t < 8 * HID; t += 512)
        xs[t >> 7][t & 127] = x[r0 * HID + t];
    __syncthreads();

    // ---- phase 1: h rows 2q, 2q+1 ----
    {
        const float bf = b_fc[k];
        float a0 = bf, a1 = bf;
        for (int d0 = 0; d0 < HID; d0 += 4) {
            const float w0 = W_fc[(d0 + 0) * HID + k];
            const float w1 = W_fc[(d0 + 1) * HID + k];
            const float w2 = W_fc[(d0 + 2) * HID + k];
            const float w3 = W_fc[(d0 + 3) * HID + k];
            const float4 x0 = *(const float4*)&xs[2 * q + 0][d0];
            const float4 x1 = *(const float4*)&xs[2 * q + 1][d0];
            a0 += x0.x * w0 + x0.y * w1 + x0.z * w2 + x0.w * w3;
            a1 += x1.x * w0 + x1.y * w1 + x1.z * w2 + x1.w * w3;
        }
        hs[2 * q + 0][k] = a0;
        hs[2 * q + 1][k] = a1;
        h[(r0 + 2 * q + 0) * HID + k] = a0;
        h[(r0 + 2 * q + 1) * HID + k] = a1;
    }
    __syncthreads();

    // ---- phase 2: q<2 -> ai, q>=2 -> aj (transposed store) ----
    {
        const int is_aj  = q >> 1;
        const int rbase  = (q & 1) * 4;
        const float* Wp  = W_a1 + is_aj * HID * HID;
        const float bias = is_aj ? 0.f : b_a1[k];
        float acc[4];
        #pragma unroll
        for (int r = 0; r < 4; ++r) acc[r] = bias;
        for (int d0 = 0; d0 < HID; d0 += 4) {
            const float w0 = Wp[(d0 + 0) * HID + k];
            const float w1 = Wp[(d0 + 1) * HID + k];
            const float w2 = Wp[(d0 + 2) * HID + k];
            const float w3 = Wp[(d0 + 3) * HID + k];
            #pragma unroll
            for (int r = 0; r < 4; ++r) {
                const float4 hv = *(const float4*)&hs[rbase + r][d0];
                acc[r] += hv.x * w0 + hv.y * w1 + hv.z * w2 + hv.w * w3;
            }
        }
        if (!is_aj) {
            #pragma unroll
            for (int r = 0; r < 4; ++r)
                ai[(r0 + rbase + r) * HID + k] = acc[r];
        } else {
            const float4 v = {acc[0], acc[1], acc[2], acc[3]};
            *(float4*)&ajT[(b * HID + k) * NN + n0 + rbase] = v;
        }
    }
}

// ---------------------------------------------------------------------------
// K2: per (batch, 8-row i-tile), 512 threads (8 waves). Phase A: one wave
// per i-row, lane l owns j=4l..4l+3, reads ajT coalesced, softmax is
// wave-local (shfl only). Phase B/C: thread (k, g) computes rows 2g,2g+1.
// ---------------------------------------------------------------------------
__global__ __launch_bounds__(512) void gat_k2(
    const float* __restrict__ ai, const float* __restrict__ ajT,
    const float* __restrict__ h,  const int* __restrict__ adj,
    const float* __restrict__ w_a2, const float* __restrict__ b_a2,
    const float* __restrict__ W_out, const float* __restrict__ b_out,
    float* __restrict__ out)
{
    __shared__ __align__(16) float ais[8][HID];
    __shared__ __align__(16) float w2s[HID];
    __shared__ __align__(16) float p_lds[8][NN];
    __shared__ __align__(16) float hps[8][HID];

    const int tid = threadIdx.x;
    const int b   = blockIdx.x >> 5;
    const int i0  = (blockIdx.x & 31) * 8;

    for (int t = tid; t < 8 * HID; t += 512)
        ais[t >> 7][t & 127] = ai[(b * NN + i0) * HID + t];
    if (tid < HID) w2s[tid] = w_a2[tid];
    __syncthreads();

    // ---- phase A: e + wave-local softmax ----
    {
        const int wid = tid >> 6, lane = tid & 63;
        const int j0 = lane * 4;
        float4 acc = {0.f, 0.f, 0.f, 0.f};
        const float* ajp = ajT + b * HID * NN + j0;
        #pragma unroll 4
        for (int kk = 0; kk < HID; ++kk) {
            const float4 a4 = *(const float4*)(ajp + kk * NN);
            const float aik = ais[wid][kk];
            const float wk  = w2s[kk];
            acc.x += fmaxf(aik + a4.x, 0.f) * wk;
            acc.y += fmaxf(aik + a4.y, 0.f) * wk;
            acc.z += fmaxf(aik + a4.z, 0.f) * wk;
            acc.w += fmaxf(aik + a4.w, 0.f) * wk;
        }
        const float ba2 = b_a2[0];
        const int4 am = *(const int4*)(adj + (b * NN + i0 + wid) * NN + j0);
        const float e0 = am.x ? acc.x + ba2 : -1e9f;
        const float e1 = am.y ? acc.y + ba2 : -1e9f;
        const float e2 = am.z ? acc.z + ba2 : -1e9f;
        const float e3 = am.w ? acc.w + ba2 : -1e9f;
        float m = fmaxf(fmaxf(e0, e1), fmaxf(e2, e3));
        #pragma unroll
        for (int off = 32; off; off >>= 1) m = fmaxf(m, __shfl_xor(m, off));
        const float p0 = __expf(e0 - m), p1 = __expf(e1 - m);
        const float p2 = __expf(e2 - m), p3 = __expf(e3 - m);
        float s = (p0 + p1) + (p2 + p3);
        #pragma unroll
        for (int off = 32; off; off >>= 1) s += __shfl_xor(s, off);
        const float inv = 1.f / s;
        const float4 pv = {p0 * inv, p1 * inv, p2 * inv, p3 * inv};
        *(float4*)&p_lds[wid][j0] = pv;
    }
    __syncthreads();

    const int k = tid & 127, g = tid >> 7;   // rows 2g, 2g+1

    // ---- phase B: h' = attn @ h ----
    {
        float hp0 = 0.f, hp1 = 0.f;
        const float* hb = h + b * NN * HID + k;
        #pragma unroll 2
        for (int j = 0; j < NN; j += 4) {
            const float4 pA = *(const float4*)&p_lds[2 * g + 0][j];
            const float4 pB = *(const float4*)&p_lds[2 * g + 1][j];
            const float h0 = hb[(j + 0) * HID];
            const float h1 = hb[(j + 1) * HID];
            const float h2 = hb[(j + 2) * HID];
            const float h3 = hb[(j + 3) * HID];
            hp0 += pA.x * h0 + pA.y * h1 + pA.z * h2 + pA.w * h3;
            hp1 += pB.x * h0 + pB.y * h1 + pB.z * h2 + pB.w * h3;
        }
        hps[2 * g + 0][k] = hp0;
        hps[2 * g + 1][k] = hp1;
    }
    __syncthreads();

    // ---- phase C: out = h' @ W_out + b_out ----
    {
        const float bo = b_out[k];
        float o0 = bo, o1 = bo;
        for (int d0 = 0; d0 < HID; d0 += 4) {
            const float w0 = W_out[(d0 + 0) * HID + k];
            const float w1 = W_out[(d0 + 1) * HID + k];
            const float w2 = W_out[(d0 + 2) * HID + k];
            const float w3 = W_out[(d0 + 3) * HID + k];
            const float4 hA = *(const float4*)&hps[2 * g + 0][d0];
            const float4 hB = *(const float4*)&hps[2 * g + 1][d0];
            o0 += hA.x * w0 + hA.y * w1 + hA.z * w2 + hA.w * w3;
            o1 += hB.x * w0 + hB.y * w1 + hB.z * w2 + hB.w * w3;
        }
        out[(b * NN + i0 + 2 * g + 0) * HID + k] = o0;
        out[(b * NN + i0 + 2 * g + 1) * HID + k] = o1;
    }
}

extern "C" void kernel_launch(void* const* d_in, const int* in_sizes, int n_in,
                              void* d_out, int out_size, void* d_ws, size_t ws_size,
                              hipStream_t stream) {
    const float* x     = (const float*)d_in[0];
    const int*   adj   = (const int*)  d_in[1];
    const float* W_fc  = (const float*)d_in[2];
    const float* b_fc  = (const float*)d_in[3];
    const float* W_a1  = (const float*)d_in[4];
    const float* b_a1  = (const float*)d_in[5];
    const float* w_a2  = (const float*)d_in[6];
    const float* b_a2  = (const float*)d_in[7];
    const float* W_out = (const float*)d_in[8];
    const float* b_out = (const float*)d_in[9];
    float* out = (float*)d_out;

    float* ws  = (float*)d_ws;
    float* h   = ws;                       // 16*256*128
    float* ai  = ws + BS * NN * HID;       // +524288
    float* ajT = ws + 2 * BS * NN * HID;   // +1048576 (ajT[b][k][j])

    gat_k1<<<BS * NN / 8, 512, 0, stream>>>(x, W_fc, b_fc, W_a1, b_a1, h, ai, ajT);
    gat_k2<<<BS * (NN / 8), 512, 0, stream>>>(ai, ajT, h, adj, w_a2, b_a2,
                                              W_out, b_out, out);
}

// Round 3
// 54.290 us; speedup vs baseline: 1.3515x; 1.0824x over previous
//
#include <hip/hip_runtime.h>

#define BS  16
#define NN  256
#define HID 128

// ---------------------------------------------------------------------------
// K1: 8 flat rows per block, 512 threads (4 quarters of 128 = one k-column
// each). Phase 1: quarter q computes h for rows 2q,2q+1. Phase 2: quarters
// 0,1 compute ai (rows 0-3 / 4-7), quarters 2,3 compute aj and store it
// TRANSPOSED as ajT[b][k][j] so K2's staging is coalesced.
// ---------------------------------------------------------------------------
__global__ __launch_bounds__(512) void gat_k1(
    const float* __restrict__ x, const float* __restrict__ W_fc,
    const float* __restrict__ b_fc, const float* __restrict__ W_a1,
    const float* __restrict__ b_a1,
    float* __restrict__ h, float* __restrict__ ai, float* __restrict__ ajT)
{
    __shared__ __align__(16) float xs[8][HID];
    __shared__ __align__(16) float hs[8][HID];
    const int tid = threadIdx.x;
    const int k   = tid & 127;
    const int q   = tid >> 7;          // 0..3
    const int r0  = blockIdx.x * 8;    // flat row (= b*NN + n)
    const int b   = r0 >> 8;
    const int n0  = r0 & 255;

    for (int t = tid; t < 8 * HID; t += 512)
        xs[t >> 7][t & 127] = x[r0 * HID + t];
    __syncthreads();

    // ---- phase 1: h rows 2q, 2q+1 ----
    {
        const float bf = b_fc[k];
        float a0 = bf, a1 = bf;
        #pragma unroll 4
        for (int d0 = 0; d0 < HID; d0 += 4) {
            const float w0 = W_fc[(d0 + 0) * HID + k];
            const float w1 = W_fc[(d0 + 1) * HID + k];
            const float w2 = W_fc[(d0 + 2) * HID + k];
            const float w3 = W_fc[(d0 + 3) * HID + k];
            const float4 x0 = *(const float4*)&xs[2 * q + 0][d0];
            const float4 x1 = *(const float4*)&xs[2 * q + 1][d0];
            a0 += x0.x * w0 + x0.y * w1 + x0.z * w2 + x0.w * w3;
            a1 += x1.x * w0 + x1.y * w1 + x1.z * w2 + x1.w * w3;
        }
        hs[2 * q + 0][k] = a0;
        hs[2 * q + 1][k] = a1;
        h[(r0 + 2 * q + 0) * HID + k] = a0;
        h[(r0 + 2 * q + 1) * HID + k] = a1;
    }
    __syncthreads();

    // ---- phase 2: q<2 -> ai, q>=2 -> ajT ----
    {
        const int is_aj  = q >> 1;
        const int rbase  = (q & 1) * 4;
        const float* Wp  = W_a1 + is_aj * HID * HID;
        const float bias = is_aj ? 0.f : b_a1[k];
        float acc[4];
        #pragma unroll
        for (int r = 0; r < 4; ++r) acc[r] = bias;
        #pragma unroll 4
        for (int d0 = 0; d0 < HID; d0 += 4) {
            const float w0 = Wp[(d0 + 0) * HID + k];
            const float w1 = Wp[(d0 + 1) * HID + k];
            const float w2 = Wp[(d0 + 2) * HID + k];
            const float w3 = Wp[(d0 + 3) * HID + k];
            #pragma unroll
            for (int r = 0; r < 4; ++r) {
                const float4 hv = *(const float4*)&hs[rbase + r][d0];
                acc[r] += hv.x * w0 + hv.y * w1 + hv.z * w2 + hv.w * w3;
            }
        }
        if (!is_aj) {
            #pragma unroll
            for (int r = 0; r < 4; ++r)
                ai[(r0 + rbase + r) * HID + k] = acc[r];
        } else {
            const float4 v = {acc[0], acc[1], acc[2], acc[3]};
            *(float4*)&ajT[(b * HID + k) * NN + n0 + rbase] = v;
        }
    }
}

// ---------------------------------------------------------------------------
// K2: per (batch, 8-row i-tile), 512 threads (8 waves). Phase A: aj staged
// in LDS per 32-k chunk (coalesced once per block, reg-prefetch of next
// chunk), wave = i-row, lane owns j=4l..4l+3, conflict-free b128 LDS reads,
// wave-local softmax. Phase B/C as before.
// ---------------------------------------------------------------------------
__global__ __launch_bounds__(512, 4) void gat_k2(
    const float* __restrict__ ai, const float* __restrict__ ajT,
    const float* __restrict__ h,  const int* __restrict__ adj,
    const float* __restrict__ w_a2, const float* __restrict__ b_a2,
    const float* __restrict__ W_out, const float* __restrict__ b_out,
    float* __restrict__ out)
{
    __shared__ __align__(16) float2 aiw[8][HID];      // {ai, w2} packed, 8 KB
    __shared__ __align__(16) float  ajs[32][NN];      // 32 KB chunk
    __shared__ __align__(16) float  p_lds[8][NN];     // 8 KB
    __shared__ __align__(16) float  hps[8][HID];      // 4 KB

    const int tid  = threadIdx.x;
    const int b    = blockIdx.x >> 5;
    const int i0   = (blockIdx.x & 31) * 8;
    const int wid  = tid >> 6, lane = tid & 63;
    const int j0   = lane * 4;

    // stage {ai, w2} interleaved
    for (int t = tid; t < 8 * HID; t += 512) {
        const int i = t >> 7, kk = t & 127;
        float2 v;
        v.x = ai[(b * NN + i0 + i) * HID + kk];
        v.y = w_a2[kk];
        aiw[i][kk] = v;
    }

    // staging-row assignment: thread covers ajs[tid>>4][(tid&15)*16 .. +15]
    const int srow = tid >> 4, scol = (tid & 15) * 16;
    const float* ajbase = ajT + (b * HID + srow) * NN + scol;

    float4 st0, st1, st2, st3;
    st0 = *(const float4*)(ajbase + 0);
    st1 = *(const float4*)(ajbase + 4);
    st2 = *(const float4*)(ajbase + 8);
    st3 = *(const float4*)(ajbase + 12);

    float4 acc = {0.f, 0.f, 0.f, 0.f};
    for (int kc = 0; kc < 4; ++kc) {
        __syncthreads();   // prior chunk compute done (also covers aiw fill)
        *(float4*)&ajs[srow][scol + 0]  = st0;
        *(float4*)&ajs[srow][scol + 4]  = st1;
        *(float4*)&ajs[srow][scol + 8]  = st2;
        *(float4*)&ajs[srow][scol + 12] = st3;
        if (kc < 3) {
            const float* nxt = ajbase + (kc + 1) * 32 * NN;
            st0 = *(const float4*)(nxt + 0);
            st1 = *(const float4*)(nxt + 4);
            st2 = *(const float4*)(nxt + 8);
            st3 = *(const float4*)(nxt + 12);
        }
        __syncthreads();   // chunk ready
        const float2* aiwr = &aiw[wid][kc * 32];
        #pragma unroll 8
        for (int kk = 0; kk < 32; ++kk) {
            const float4 a4 = *(const float4*)&ajs[kk][j0];
            const float2 aw = aiwr[kk];
            acc.x += fmaxf(aw.x + a4.x, 0.f) * aw.y;
            acc.y += fmaxf(aw.x + a4.y, 0.f) * aw.y;
            acc.z += fmaxf(aw.x + a4.z, 0.f) * aw.y;
            acc.w += fmaxf(aw.x + a4.w, 0.f) * aw.y;
        }
    }

    // ---- mask + wave-local softmax ----
    {
        const float ba2 = b_a2[0];
        const int4 am = *(const int4*)(adj + (b * NN + i0 + wid) * NN + j0);
        const float e0 = am.x ? acc.x + ba2 : -1e9f;
        const float e1 = am.y ? acc.y + ba2 : -1e9f;
        const float e2 = am.z ? acc.z + ba2 : -1e9f;
        const float e3 = am.w ? acc.w + ba2 : -1e9f;
        float m = fmaxf(fmaxf(e0, e1), fmaxf(e2, e3));
        #pragma unroll
        for (int off = 32; off; off >>= 1) m = fmaxf(m, __shfl_xor(m, off));
        const float p0 = __expf(e0 - m), p1 = __expf(e1 - m);
        const float p2 = __expf(e2 - m), p3 = __expf(e3 - m);
        float s = (p0 + p1) + (p2 + p3);
        #pragma unroll
        for (int off = 32; off; off >>= 1) s += __shfl_xor(s, off);
        const float inv = 1.f / s;
        const float4 pv = {p0 * inv, p1 * inv, p2 * inv, p3 * inv};
        *(float4*)&p_lds[wid][j0] = pv;
    }
    __syncthreads();

    const int k = tid & 127, g = tid >> 7;   // rows 2g, 2g+1

    // ---- phase B: h' = attn @ h ----
    {
        float hp0 = 0.f, hp1 = 0.f;
        const float* hb = h + b * NN * HID + k;
        #pragma unroll 2
        for (int j = 0; j < NN; j += 4) {
            const float4 pA = *(const float4*)&p_lds[2 * g + 0][j];
            const float4 pB = *(const float4*)&p_lds[2 * g + 1][j];
            const float h0 = hb[(j + 0) * HID];
            const float h1 = hb[(j + 1) * HID];
            const float h2 = hb[(j + 2) * HID];
            const float h3 = hb[(j + 3) * HID];
            hp0 += pA.x * h0 + pA.y * h1 + pA.z * h2 + pA.w * h3;
            hp1 += pB.x * h0 + pB.y * h1 + pB.z * h2 + pB.w * h3;
        }
        hps[2 * g + 0][k] = hp0;
        hps[2 * g + 1][k] = hp1;
    }
    __syncthreads();

    // ---- phase C: out = h' @ W_out + b_out ----
    {
        const float bo = b_out[k];
        float o0 = bo, o1 = bo;
        #pragma unroll 4
        for (int d0 = 0; d0 < HID; d0 += 4) {
            const float w0 = W_out[(d0 + 0) * HID + k];
            const float w1 = W_out[(d0 + 1) * HID + k];
            const float w2 = W_out[(d0 + 2) * HID + k];
            const float w3 = W_out[(d0 + 3) * HID + k];
            const float4 hA = *(const float4*)&hps[2 * g + 0][d0];
            const float4 hB = *(const float4*)&hps[2 * g + 1][d0];
            o0 += hA.x * w0 + hA.y * w1 + hA.z * w2 + hA.w * w3;
            o1 += hB.x * w0 + hB.y * w1 + hB.z * w2 + hB.w * w3;
        }
        out[(b * NN + i0 + 2 * g + 0) * HID + k] = o0;
        out[(b * NN + i0 + 2 * g + 1) * HID + k] = o1;
    }
}

extern "C" void kernel_launch(void* const* d_in, const int* in_sizes, int n_in,
                              void* d_out, int out_size, void* d_ws, size_t ws_size,
                              hipStream_t stream) {
    const float* x     = (const float*)d_in[0];
    const int*   adj   = (const int*)  d_in[1];
    const float* W_fc  = (const float*)d_in[2];
    const float* b_fc  = (const float*)d_in[3];
    const float* W_a1  = (const float*)d_in[4];
    const float* b_a1  = (const float*)d_in[5];
    const float* w_a2  = (const float*)d_in[6];
    const float* b_a2  = (const float*)d_in[7];
    const float* W_out = (const float*)d_in[8];
    const float* b_out = (const float*)d_in[9];
    float* out = (float*)d_out;

    float* ws  = (float*)d_ws;
    float* h   = ws;                       // 16*256*128
    float* ai  = ws + BS * NN * HID;       // +524288
    float* ajT = ws + 2 * BS * NN * HID;   // +1048576 (ajT[b][k][j])

    gat_k1<<<BS * NN / 8, 512, 0, stream>>>(x, W_fc, b_fc, W_a1, b_a1, h, ai, ajT);
    gat_k2<<<BS * (NN / 8), 512, 0, stream>>>(ai, ajT, h, adj, w_a2, b_a2,
                                              W_out, b_out, out);
}